// Round 10
// baseline (68.392 us; speedup 1.0000x reference)
//
#include <hip/hip_runtime.h>
#include <math.h>

#define BB 4
#define NN 512
#define PP 2048
#define EE 32768
#define FH 128
#define DRBF 32
#define CUT 4.0f
#define PI_F 3.14159265358979323846f
#define NE 4              // edges per MLP iteration
#define CHUNK 512         // raw edges per block
#define ATILE 8           // atoms per block in atom_kernel

// ws layout: O at ws+256: [2048 atoms][640] floats = 5.24 MB
//   O[a][  0..127] = M0 (r_hat.x weights)   = V[a][0] @ W1_q
//   O[a][128..255] = M1                      = V[a][1] @ W1_q
//   O[a][256..383] = M2                      = V[a][2] @ W1_q
//   O[a][384..511] = Cn = n_e[a] @ W1_n
//   O[a][512..639] = Cs = S[a]  @ W1_s

__global__ __launch_bounds__(256) void init_out(float* __restrict__ out) {
  int i = blockIdx.x * 256 + threadIdx.x;
  ((float4*)out)[i] = make_float4(0.f, 0.f, 0.f, 0.f);
}

// Per-atom precompute: block = 8 atoms, 640 threads = (fam 0..4) x (f1 0..127).
// fams 0-2 share W1_q rows. Inputs staged in LDS; weights ping-pong registers.
__global__ __launch_bounds__(640) void atom_kernel(
    const float* __restrict__ S, const float* __restrict__ V,
    const float* __restrict__ W1, float* __restrict__ O) {
  __shared__ float inS[ATILE][5][128];   // V0,V1,V2,S,ne = 20 KB
  const int t = threadIdx.x;
  const int a0 = blockIdx.x * ATILE;

  // stage V (3x128) + S (128) per atom: ATILE*128 float4
  for (int idx = t; idx < ATILE * 128; idx += 640) {
    int a = idx >> 7;
    int w = idx & 127;              // float4 within atom: 0..95 = V, 96..127 = S
    float4 v;
    if (w < 96) v = ((const float4*)V)[(a0 + a) * 96 + w];
    else        v = ((const float4*)S)[(a0 + a) * 32 + (w - 96)];
    int sec = (w < 96) ? (w >> 5) : 3;
    int k4  = (w < 96) ? (w & 31) : (w - 96);
    *(float4*)&inS[a][sec][k4 * 4] = v;
  }
  __syncthreads();
  for (int idx = t; idx < ATILE * 128; idx += 640) {
    int a = idx >> 7, f = idx & 127;
    float v0 = inS[a][0][f], v1 = inS[a][1][f], v2 = inS[a][2][f];
    inS[a][4][f] = sqrtf(v0*v0 + v1*v1 + v2*v2);
  }
  __syncthreads();

  const int fam = t >> 7;          // 0..4
  const int f1  = t & 127;
  const int wrow = (fam < 3) ? 32 : ((fam == 3) ? 160 : 288);
  const int sec  = (fam < 3) ? fam : ((fam == 3) ? 4 : 3);
  const float* Wb = W1 + wrow * FH + f1;

  float acc[ATILE];
  #pragma unroll
  for (int a = 0; a < ATILE; ++a) acc[a] = 0.f;
  float wA[16], wB[16];
  #pragma unroll
  for (int i = 0; i < 16; ++i) wA[i] = Wb[i * FH];

  #pragma unroll 1
  for (int g = 0; g < 4; ++g) {          // 8 groups of 16 k (K=128)
    const int kA = g * 32, kB = g * 32 + 16;
    #pragma unroll
    for (int i = 0; i < 16; ++i) wB[i] = Wb[(kB + i) * FH];
    #pragma unroll
    for (int q = 0; q < 4; ++q) {
      #pragma unroll
      for (int a = 0; a < ATILE; ++a) {
        float4 hv = *(const float4*)&inS[a][sec][kA + q*4];
        acc[a] = fmaf(hv.x, wA[q*4+0], acc[a]);
        acc[a] = fmaf(hv.y, wA[q*4+1], acc[a]);
        acc[a] = fmaf(hv.z, wA[q*4+2], acc[a]);
        acc[a] = fmaf(hv.w, wA[q*4+3], acc[a]);
      }
    }
    if (g < 3) {
      #pragma unroll
      for (int i = 0; i < 16; ++i) wA[i] = Wb[(kA + 32 + i) * FH];
    }
    #pragma unroll
    for (int q = 0; q < 4; ++q) {
      #pragma unroll
      for (int a = 0; a < ATILE; ++a) {
        float4 hv = *(const float4*)&inS[a][sec][kB + q*4];
        acc[a] = fmaf(hv.x, wB[q*4+0], acc[a]);
        acc[a] = fmaf(hv.y, wB[q*4+1], acc[a]);
        acc[a] = fmaf(hv.z, wB[q*4+2], acc[a]);
        acc[a] = fmaf(hv.w, wB[q*4+3], acc[a]);
      }
    }
  }
  #pragma unroll
  for (int a = 0; a < ATILE; ++a)
    O[(size_t)(a0 + a) * 640 + fam * 128 + f1] = acc[a];
}

// Fused filter + per-edge MLP. Block = 256 thr / 4 waves owns 512 raw edges.
// Survivors in LDS; W1_rbf + W2 + b1 staged in LDS once; per edge only a
// 2.5 KB coalesced O-row gather + small compute. One atomic per edge.
__global__ __launch_bounds__(256) void fused_kernel(
    const int* __restrict__ pe, const float* __restrict__ pdisp,
    const float* __restrict__ cell, const float* __restrict__ atom_xyz,
    const float* __restrict__ probe_xyz,
    const float* __restrict__ O,
    const float* __restrict__ W1, const float* __restrict__ b1,
    const float* __restrict__ W2, const float* __restrict__ b2,
    const float* __restrict__ W3, const float* __restrict__ b3,
    float* __restrict__ out) {
  __shared__ float sdx[CHUNK], sdy[CHUNK], sdz[CHUNK];   // 6 KB
  __shared__ unsigned sap[CHUNK];                        // 2 KB
  __shared__ int mcnt;
  __shared__ float w1S[DRBF * FH];       // 16 KB  [k][f1]
  __shared__ float w2S[FH * 65];         // 33.3 KB [k][65] (pad -> conflict-free)
  __shared__ float b1S[FH];
  __shared__ float epS[NE][DRBF];
  __shared__ float h2S[NE][FH];
  __shared__ float rS[NE][3];
  __shared__ unsigned aS[NE];
  __shared__ float cwS[NE];
  __shared__ unsigned pS[NE];

  const int t    = threadIdx.x;
  const int lane = t & 63;
  const int wave = t >> 6;
  if (t == 0) mcnt = 0;

  // ---- stage small weights into LDS (once per block) ----
  for (int i = t; i < DRBF * FH; i += 256) w1S[i] = W1[i];          // rows 0..31
  for (int i = t; i < FH * 64;  i += 256) w2S[(i >> 6) * 65 + (i & 63)] = W2[i];
  if (t < FH) b1S[t] = b1[t];
  __syncthreads();

  // ---- Phase F: filter this block's 512 edges ----
  const int base = blockIdx.x * CHUNK;
  const int b = base >> 15;
  const float* cb = cell + b * 9;
  const float c00=cb[0],c01=cb[1],c02=cb[2],
              c10=cb[3],c11=cb[4],c12=cb[5],
              c20=cb[6],c21=cb[7],c22=cb[8];
  #pragma unroll
  for (int i = 0; i < 2; ++i) {
    const int e = base + t + i * 256;
    int2 ap = ((const int2*)pe)[e];
    float pd0 = pdisp[e*3], pd1 = pdisp[e*3+1], pd2 = pdisp[e*3+2];
    float d0 = pd0*c00 + pd1*c10 + pd2*c20;
    float d1 = pd0*c01 + pd1*c11 + pd2*c21;
    float d2 = pd0*c02 + pd1*c12 + pd2*c22;
    int ag = b*NN + ap.x;
    int pg = b*PP + ap.y;
    float dx = probe_xyz[pg*3]   - (atom_xyz[ag*3]   + d0);
    float dy = probe_xyz[pg*3+1] - (atom_xyz[ag*3+1] + d1);
    float dz = probe_xyz[pg*3+2] - (atom_xyz[ag*3+2] + d2);
    float dist2 = dx*dx + dy*dy + dz*dz;
    if (dist2 < CUT*CUT) {
      int s = atomicAdd(&mcnt, 1);   // LDS atomic
      sdx[s] = dx; sdy[s] = dy; sdz[s] = dz;
      sap[s] = ((unsigned)ag << 16) | (unsigned)pg;
    }
  }
  __syncthreads();
  const int m = mcnt;
  if (m == 0) return;

  const int f1 = t & 127;     // L1 feature
  const int eh = t >> 7;      // L1 edge-half (edges eh*2, eh*2+1)
  const float b2v = b2[lane];
  const float w3v = W3[lane];
  const float b3v = b3[0];

  for (int s0 = 0; s0 < m; s0 += NE) {
    // ---- per-edge prep: wave w handles survivor s0+w ----
    {
      const int s = s0 + wave;
      float dx, dy, dz; unsigned ap_;
      if (s < m) { dx = sdx[s]; dy = sdy[s]; dz = sdz[s]; ap_ = sap[s]; }
      else       { dx = 1.f; dy = 0.f; dz = 0.f; ap_ = 0xFFFFFFFFu; }
      float d = sqrtf(dx*dx + dy*dy + dz*dz);
      float inv = 1.0f / (d + 1e-8f);
      if (lane < DRBF) epS[wave][lane] = sinf(d * (float)(lane+1) * (PI_F/CUT)) / d;
      if (lane == 0) {
        rS[wave][0] = dx*inv; rS[wave][1] = dy*inv; rS[wave][2] = dz*inv;
        aS[wave] = (ap_ == 0xFFFFFFFFu) ? 0u : (ap_ >> 16);
        cwS[wave] = 0.5f * (cosf((PI_F/CUT) * d) + 1.0f);
        pS[wave]  = (ap_ == 0xFFFFFFFFu) ? 0xFFFFFFFFu : (ap_ & 0xFFFFu);
      }
    }
    __syncthreads();

    // ---- L1: thread (f1, eh) assembles z for edges eh*2, eh*2+1 ----
    {
      const int e0 = eh*2, e1 = eh*2 + 1;
      const float* Ob0 = O + (size_t)aS[e0] * 640 + f1;
      const float* Ob1 = O + (size_t)aS[e1] * 640 + f1;
      float o00 = Ob0[0], o01 = Ob0[128], o02 = Ob0[256], o03 = Ob0[384], o04 = Ob0[512];
      float o10 = Ob1[0], o11 = Ob1[128], o12 = Ob1[256], o13 = Ob1[384], o14 = Ob1[512];
      float bb = b1S[f1];
      float z0 = bb + o03 + o04 + rS[e0][0]*o00 + rS[e0][1]*o01 + rS[e0][2]*o02;
      float z1 = bb + o13 + o14 + rS[e1][0]*o10 + rS[e1][1]*o11 + rS[e1][2]*o12;
      #pragma unroll 8
      for (int k = 0; k < DRBF; ++k) {
        float w = w1S[k * FH + f1];
        z0 = fmaf(epS[e0][k], w, z0);
        z1 = fmaf(epS[e1][k], w, z1);
      }
      h2S[e0][f1] = z0 / (1.0f + __expf(-z0));
      h2S[e1][f1] = z1 / (1.0f + __expf(-z1));
    }
    __syncthreads();

    // ---- L2: wave = edge, lane = out-feature (64); W2 from LDS ----
    float acc2 = b2v;
    {
      const float* hp = &h2S[wave][0];
      #pragma unroll 8
      for (int k4 = 0; k4 < FH/4; ++k4) {
        float4 hv = *(const float4*)(hp + k4*4);
        acc2 = fmaf(hv.x, w2S[(k4*4+0)*65 + lane], acc2);
        acc2 = fmaf(hv.y, w2S[(k4*4+1)*65 + lane], acc2);
        acc2 = fmaf(hv.z, w2S[(k4*4+2)*65 + lane], acc2);
        acc2 = fmaf(hv.w, w2S[(k4*4+3)*65 + lane], acc2);
      }
    }

    // ---- L3: silu, dot with W3 across lanes, scatter ----
    {
      float h2 = acc2 / (1.0f + __expf(-acc2));
      float rs = h2 * w3v;
      #pragma unroll
      for (int off = 32; off; off >>= 1) rs += __shfl_xor(rs, off, 64);
      if (lane == 0) {
        unsigned p = pS[wave];
        if (p != 0xFFFFFFFFu) atomicAdd(&out[p], (rs + b3v) * cwS[wave]);
      }
    }
    __syncthreads();
  }
}

extern "C" void kernel_launch(void* const* d_in, const int* in_sizes, int n_in,
                              void* d_out, int out_size, void* d_ws, size_t ws_size,
                              hipStream_t stream) {
  const float* S         = (const float*)d_in[0];
  const float* V         = (const float*)d_in[1];
  const float* atom_xyz  = (const float*)d_in[2];
  const float* probe_xyz = (const float*)d_in[3];
  const float* cell      = (const float*)d_in[4];
  const float* pdisp     = (const float*)d_in[5];
  const float* W1        = (const float*)d_in[6];
  const float* b1        = (const float*)d_in[7];
  const float* W2        = (const float*)d_in[8];
  const float* b2        = (const float*)d_in[9];
  const float* W3        = (const float*)d_in[10];
  const float* b3        = (const float*)d_in[11];
  const int*   pe        = (const int*)d_in[12];
  float* out = (float*)d_out;

  float* O = (float*)((char*)d_ws + 256);   // 2048 x 640 floats

  init_out<<<8, 256, 0, stream>>>(out);
  atom_kernel<<<BB*NN/ATILE, 640, 0, stream>>>(S, V, W1, O);
  fused_kernel<<<BB*EE/CHUNK, 256, 0, stream>>>(pe, pdisp, cell, atom_xyz, probe_xyz,
                                                O, W1, b1, W2, b2, W3, b3, out);
}

// Round 11
// 29.737 us; speedup vs baseline: 2.2999x; 2.2999x over previous
//
#include <hip/hip_runtime.h>
#include <math.h>

#define BB 4
#define NN 512
#define PP 2048
#define EE 32768
#define FH 128
#define DRBF 32
#define CUT 4.0f
#define PI_F 3.14159265358979323846f
#define NE 4              // edges per MLP iteration
#define CHUNK 256         // raw edges per block (512 blocks -> 2/CU)
#define AT2 8             // atoms per block in atom_kernel
#define W2P 68            // w2S padded row stride (16B-aligned, conflict-free)

// ws layout: O at ws+256: [2048 atoms][640] floats = 5.24 MB
//   O[a][  0..127] = M0 = V[a][0] @ W1_q      (rows  32..159)
//   O[a][128..255] = M1 = V[a][1] @ W1_q
//   O[a][256..383] = M2 = V[a][2] @ W1_q
//   O[a][384..511] = Cn = n_e[a]  @ W1_n      (rows 160..287)
//   O[a][512..639] = Cs = S[a]    @ W1_s      (rows 288..415)

__global__ __launch_bounds__(256) void init_out(float* __restrict__ out) {
  int i = blockIdx.x * 256 + threadIdx.x;
  ((float4*)out)[i] = make_float4(0.f, 0.f, 0.f, 0.f);
}

// Per-atom precompute, TLP-first: 1280 blocks (256 atom-groups x 5 fams),
// 256 threads = (f1 in 128) x (atom-half in 2), acc[4] only -> no spill.
__global__ __launch_bounds__(256) void atom_kernel(
    const float* __restrict__ S, const float* __restrict__ V,
    const float* __restrict__ W1, float* __restrict__ O) {
  __shared__ float inS[AT2][128];   // 4 KB
  const int t   = threadIdx.x;
  const int fam = blockIdx.x % 5;
  const int a0  = (blockIdx.x / 5) * AT2;

  // stage the needed 128-vector per atom
  {
    int a  = t >> 5;          // 0..7
    int k4 = t & 31;          // float4 index 0..31
    float4 v;
    if (fam < 3) {
      v = *(const float4*)&V[(size_t)(a0 + a) * 384 + fam * 128 + k4 * 4];
    } else if (fam == 4) {
      v = *(const float4*)&S[(size_t)(a0 + a) * 128 + k4 * 4];
    } else { // fam == 3: n_e from V
      float4 x = *(const float4*)&V[(size_t)(a0 + a) * 384 +   0 + k4 * 4];
      float4 y = *(const float4*)&V[(size_t)(a0 + a) * 384 + 128 + k4 * 4];
      float4 z = *(const float4*)&V[(size_t)(a0 + a) * 384 + 256 + k4 * 4];
      v.x = sqrtf(x.x*x.x + y.x*y.x + z.x*z.x);
      v.y = sqrtf(x.y*x.y + y.y*y.y + z.y*z.y);
      v.z = sqrtf(x.z*x.z + y.z*y.z + z.z*z.z);
      v.w = sqrtf(x.w*x.w + y.w*y.w + z.w*z.w);
    }
    *(float4*)&inS[a][k4 * 4] = v;
  }
  __syncthreads();

  const int f1 = t & 127;
  const int ah = t >> 7;     // atom half: atoms ah*4 .. ah*4+3
  const int wrow = (fam < 3) ? 32 : ((fam == 3) ? 160 : 288);
  const float* Wb = W1 + (size_t)wrow * FH + f1;

  float acc0 = 0.f, acc1 = 0.f, acc2 = 0.f, acc3 = 0.f;
  #pragma unroll 4
  for (int k4 = 0; k4 < 32; ++k4) {
    float w0 = Wb[(k4*4 + 0) * FH];
    float w1 = Wb[(k4*4 + 1) * FH];
    float w2 = Wb[(k4*4 + 2) * FH];
    float w3 = Wb[(k4*4 + 3) * FH];
    float4 h0 = *(const float4*)&inS[ah*4 + 0][k4*4];
    float4 h1 = *(const float4*)&inS[ah*4 + 1][k4*4];
    float4 h2 = *(const float4*)&inS[ah*4 + 2][k4*4];
    float4 h3 = *(const float4*)&inS[ah*4 + 3][k4*4];
    acc0 = fmaf(h0.x, w0, acc0); acc1 = fmaf(h1.x, w0, acc1);
    acc2 = fmaf(h2.x, w0, acc2); acc3 = fmaf(h3.x, w0, acc3);
    acc0 = fmaf(h0.y, w1, acc0); acc1 = fmaf(h1.y, w1, acc1);
    acc2 = fmaf(h2.y, w1, acc2); acc3 = fmaf(h3.y, w1, acc3);
    acc0 = fmaf(h0.z, w2, acc0); acc1 = fmaf(h1.z, w2, acc1);
    acc2 = fmaf(h2.z, w2, acc2); acc3 = fmaf(h3.z, w2, acc3);
    acc0 = fmaf(h0.w, w3, acc0); acc1 = fmaf(h1.w, w3, acc1);
    acc2 = fmaf(h2.w, w3, acc2); acc3 = fmaf(h3.w, w3, acc3);
  }
  float* Ob = O + (size_t)(a0 + ah*4) * 640 + fam * 128 + f1;
  Ob[0]      = acc0;
  Ob[640]    = acc1;
  Ob[1280]   = acc2;
  Ob[1920]   = acc3;
}

// Fused filter + per-edge MLP. Block = 256 thr / 4 waves owns 256 raw edges.
__global__ __launch_bounds__(256) void fused_kernel(
    const int* __restrict__ pe, const float* __restrict__ pdisp,
    const float* __restrict__ cell, const float* __restrict__ atom_xyz,
    const float* __restrict__ probe_xyz,
    const float* __restrict__ O,
    const float* __restrict__ W1, const float* __restrict__ b1,
    const float* __restrict__ W2, const float* __restrict__ b2,
    const float* __restrict__ W3, const float* __restrict__ b3,
    float* __restrict__ out) {
  __shared__ float sdx[CHUNK], sdy[CHUNK], sdz[CHUNK];   // 3 KB
  __shared__ unsigned sap[CHUNK];                        // 1 KB
  __shared__ int mcnt;
  __shared__ float w1S[DRBF * FH];       // 16 KB  [k][f1]
  __shared__ float w2S[FH * W2P];        // 34.8 KB [k][W2P]
  __shared__ float b1S[FH];
  __shared__ float epS[NE][DRBF];
  __shared__ float h2S[NE][FH];
  __shared__ float rS[NE][3];
  __shared__ unsigned aS[NE];
  __shared__ float cwS[NE];
  __shared__ unsigned pS[NE];

  const int t    = threadIdx.x;
  const int lane = t & 63;
  const int wave = t >> 6;
  if (t == 0) mcnt = 0;

  // ---- stage small weights into LDS (float4 everywhere) ----
  {
    const float4* W1f4 = (const float4*)W1;   // rows 0..31 = RBF block
    #pragma unroll
    for (int i = 0; i < 4; ++i)
      *(float4*)&w1S[(t + i * 256) * 4] = W1f4[t + i * 256];
    const float4* W2f4 = (const float4*)W2;   // [128][64]
    #pragma unroll
    for (int i = 0; i < 8; ++i) {
      int idx = t + i * 256;                  // float4 idx over 2048
      int row = idx >> 4, col = (idx & 15) * 4;
      *(float4*)&w2S[row * W2P + col] = W2f4[idx];
    }
    if (t < 32) *(float4*)&b1S[t * 4] = ((const float4*)b1)[t];
  }

  // ---- Phase F: filter this block's 256 edges (1/thread) ----
  const int e    = blockIdx.x * CHUNK + t;
  const int b    = blockIdx.x >> 7;           // 128 blocks per batch
  const float* cb = cell + b * 9;
  {
    int2 ap = ((const int2*)pe)[e];
    float pd0 = pdisp[e*3], pd1 = pdisp[e*3+1], pd2 = pdisp[e*3+2];
    float d0 = pd0*cb[0] + pd1*cb[3] + pd2*cb[6];
    float d1 = pd0*cb[1] + pd1*cb[4] + pd2*cb[7];
    float d2 = pd0*cb[2] + pd1*cb[5] + pd2*cb[8];
    int ag = b*NN + ap.x;
    int pg = b*PP + ap.y;
    float dx = probe_xyz[pg*3]   - (atom_xyz[ag*3]   + d0);
    float dy = probe_xyz[pg*3+1] - (atom_xyz[ag*3+1] + d1);
    float dz = probe_xyz[pg*3+2] - (atom_xyz[ag*3+2] + d2);
    float dist2 = dx*dx + dy*dy + dz*dz;
    if (dist2 < CUT*CUT) {
      int s = atomicAdd(&mcnt, 1);   // LDS atomic
      sdx[s] = dx; sdy[s] = dy; sdz[s] = dz;
      sap[s] = ((unsigned)ag << 16) | (unsigned)pg;
    }
  }
  __syncthreads();
  const int m = mcnt;
  if (m == 0) return;

  const int f1 = t & 127;     // L1 feature
  const int eh = t >> 7;      // L1 edge-half (edges eh*2, eh*2+1)
  const float b2v = b2[lane];
  const float w3v = W3[lane];
  const float b3v = b3[0];

  for (int s0 = 0; s0 < m; s0 += NE) {
    // ---- per-edge prep: wave w handles survivor s0+w ----
    {
      const int s = s0 + wave;
      float dx, dy, dz; unsigned ap_;
      if (s < m) { dx = sdx[s]; dy = sdy[s]; dz = sdz[s]; ap_ = sap[s]; }
      else       { dx = 1.f; dy = 0.f; dz = 0.f; ap_ = 0xFFFFFFFFu; }
      float d = sqrtf(dx*dx + dy*dy + dz*dz);
      float inv = 1.0f / (d + 1e-8f);
      if (lane < DRBF) epS[wave][lane] = sinf(d * (float)(lane+1) * (PI_F/CUT)) / d;
      if (lane == 0) {
        rS[wave][0] = dx*inv; rS[wave][1] = dy*inv; rS[wave][2] = dz*inv;
        aS[wave] = (ap_ == 0xFFFFFFFFu) ? 0u : (ap_ >> 16);
        cwS[wave] = 0.5f * (cosf((PI_F/CUT) * d) + 1.0f);
        pS[wave]  = (ap_ == 0xFFFFFFFFu) ? 0xFFFFFFFFu : (ap_ & 0xFFFFu);
      }
    }
    __syncthreads();

    // ---- L1: thread (f1, eh) assembles z for edges eh*2, eh*2+1 ----
    {
      const int e0 = eh*2, e1 = eh*2 + 1;
      const float* Ob0 = O + (size_t)aS[e0] * 640 + f1;
      const float* Ob1 = O + (size_t)aS[e1] * 640 + f1;
      float o00 = Ob0[0], o01 = Ob0[128], o02 = Ob0[256], o03 = Ob0[384], o04 = Ob0[512];
      float o10 = Ob1[0], o11 = Ob1[128], o12 = Ob1[256], o13 = Ob1[384], o14 = Ob1[512];
      float bb = b1S[f1];
      float z0 = bb + o03 + o04 + rS[e0][0]*o00 + rS[e0][1]*o01 + rS[e0][2]*o02;
      float z1 = bb + o13 + o14 + rS[e1][0]*o10 + rS[e1][1]*o11 + rS[e1][2]*o12;
      #pragma unroll 8
      for (int k = 0; k < DRBF; ++k) {
        float w = w1S[k * FH + f1];
        z0 = fmaf(epS[e0][k], w, z0);
        z1 = fmaf(epS[e1][k], w, z1);
      }
      h2S[e0][f1] = z0 / (1.0f + __expf(-z0));
      h2S[e1][f1] = z1 / (1.0f + __expf(-z1));
    }
    __syncthreads();

    // ---- L2: wave = edge, lane = out-feature (64); W2 from LDS ----
    float acc2 = b2v;
    {
      const float* hp = &h2S[wave][0];
      #pragma unroll 8
      for (int k4 = 0; k4 < FH/4; ++k4) {
        float4 hv = *(const float4*)(hp + k4*4);
        acc2 = fmaf(hv.x, w2S[(k4*4+0)*W2P + lane], acc2);
        acc2 = fmaf(hv.y, w2S[(k4*4+1)*W2P + lane], acc2);
        acc2 = fmaf(hv.z, w2S[(k4*4+2)*W2P + lane], acc2);
        acc2 = fmaf(hv.w, w2S[(k4*4+3)*W2P + lane], acc2);
      }
    }

    // ---- L3: silu, dot with W3 across lanes, scatter ----
    {
      float h2 = acc2 / (1.0f + __expf(-acc2));
      float rs = h2 * w3v;
      #pragma unroll
      for (int off = 32; off; off >>= 1) rs += __shfl_xor(rs, off, 64);
      if (lane == 0) {
        unsigned p = pS[wave];
        if (p != 0xFFFFFFFFu) atomicAdd(&out[p], (rs + b3v) * cwS[wave]);
      }
    }
    __syncthreads();
  }
}

extern "C" void kernel_launch(void* const* d_in, const int* in_sizes, int n_in,
                              void* d_out, int out_size, void* d_ws, size_t ws_size,
                              hipStream_t stream) {
  const float* S         = (const float*)d_in[0];
  const float* V         = (const float*)d_in[1];
  const float* atom_xyz  = (const float*)d_in[2];
  const float* probe_xyz = (const float*)d_in[3];
  const float* cell      = (const float*)d_in[4];
  const float* pdisp     = (const float*)d_in[5];
  const float* W1        = (const float*)d_in[6];
  const float* b1        = (const float*)d_in[7];
  const float* W2        = (const float*)d_in[8];
  const float* b2        = (const float*)d_in[9];
  const float* W3        = (const float*)d_in[10];
  const float* b3        = (const float*)d_in[11];
  const int*   pe        = (const int*)d_in[12];
  float* out = (float*)d_out;

  float* O = (float*)((char*)d_ws + 256);   // 2048 x 640 floats

  init_out<<<8, 256, 0, stream>>>(out);
  atom_kernel<<<(BB*NN/AT2)*5, 256, 0, stream>>>(S, V, W1, O);
  fused_kernel<<<BB*EE/CHUNK, 256, 0, stream>>>(pe, pdisp, cell, atom_xyz, probe_xyz,
                                                O, W1, b1, W2, b2, W3, b3, out);
}

// Round 12
// 22.303 us; speedup vs baseline: 3.0665x; 1.3333x over previous
//
#include <hip/hip_runtime.h>
#include <math.h>

#define BB 4
#define NN 512
#define PP 2048
#define EE 32768
#define FH 128
#define DRBF 32
#define CUT 4.0f
#define PI_F 3.14159265358979323846f
#define NE 4              // edges per MLP iteration
#define CHUNK 256         // raw edges per block (512 blocks -> 2/CU)
#define AT2 8             // atoms per block in atom_kernel

// ws layout: O at ws+256: [2048 atoms][640] floats = 5.24 MB
//   O[a][  0..127] = M0 = V[a][0] @ W1_q      (W1 rows  32..159)
//   O[a][128..255] = M1 = V[a][1] @ W1_q
//   O[a][256..383] = M2 = V[a][2] @ W1_q
//   O[a][384..511] = Cn = n_e[a]  @ W1_n      (W1 rows 160..287)
//   O[a][512..639] = Cs = S[a]    @ W1_s      (W1 rows 288..415)

// Node 1: per-atom precompute (TLP-first, no spill) + zero `out` (blocks 0-7).
__global__ __launch_bounds__(256) void atom_kernel(
    const float* __restrict__ S, const float* __restrict__ V,
    const float* __restrict__ W1, float* __restrict__ O,
    float* __restrict__ out) {
  __shared__ float inS[AT2][128];   // 4 KB
  const int t   = threadIdx.x;
  if (blockIdx.x < 8)
    ((float4*)out)[blockIdx.x * 256 + t] = make_float4(0.f, 0.f, 0.f, 0.f);

  const int fam = blockIdx.x % 5;
  const int a0  = (blockIdx.x / 5) * AT2;

  // stage the needed 128-vector per atom
  {
    int a  = t >> 5;          // 0..7
    int k4 = t & 31;          // float4 index 0..31
    float4 v;
    if (fam < 3) {
      v = *(const float4*)&V[(size_t)(a0 + a) * 384 + fam * 128 + k4 * 4];
    } else if (fam == 4) {
      v = *(const float4*)&S[(size_t)(a0 + a) * 128 + k4 * 4];
    } else { // fam == 3: n_e from V
      float4 x = *(const float4*)&V[(size_t)(a0 + a) * 384 +   0 + k4 * 4];
      float4 y = *(const float4*)&V[(size_t)(a0 + a) * 384 + 128 + k4 * 4];
      float4 z = *(const float4*)&V[(size_t)(a0 + a) * 384 + 256 + k4 * 4];
      v.x = sqrtf(x.x*x.x + y.x*y.x + z.x*z.x);
      v.y = sqrtf(x.y*x.y + y.y*y.y + z.y*z.y);
      v.z = sqrtf(x.z*x.z + y.z*y.z + z.z*z.z);
      v.w = sqrtf(x.w*x.w + y.w*y.w + z.w*z.w);
    }
    *(float4*)&inS[a][k4 * 4] = v;
  }
  __syncthreads();

  const int f1 = t & 127;
  const int ah = t >> 7;     // atom half: atoms ah*4 .. ah*4+3
  const int wrow = (fam < 3) ? 32 : ((fam == 3) ? 160 : 288);
  const float* Wb = W1 + (size_t)wrow * FH + f1;

  float acc0 = 0.f, acc1 = 0.f, acc2 = 0.f, acc3 = 0.f;
  #pragma unroll 4
  for (int k4 = 0; k4 < 32; ++k4) {
    float w0 = Wb[(k4*4 + 0) * FH];
    float w1 = Wb[(k4*4 + 1) * FH];
    float w2 = Wb[(k4*4 + 2) * FH];
    float w3 = Wb[(k4*4 + 3) * FH];
    float4 h0 = *(const float4*)&inS[ah*4 + 0][k4*4];
    float4 h1 = *(const float4*)&inS[ah*4 + 1][k4*4];
    float4 h2 = *(const float4*)&inS[ah*4 + 2][k4*4];
    float4 h3 = *(const float4*)&inS[ah*4 + 3][k4*4];
    acc0 = fmaf(h0.x, w0, acc0); acc1 = fmaf(h1.x, w0, acc1);
    acc2 = fmaf(h2.x, w0, acc2); acc3 = fmaf(h3.x, w0, acc3);
    acc0 = fmaf(h0.y, w1, acc0); acc1 = fmaf(h1.y, w1, acc1);
    acc2 = fmaf(h2.y, w1, acc2); acc3 = fmaf(h3.y, w1, acc3);
    acc0 = fmaf(h0.z, w2, acc0); acc1 = fmaf(h1.z, w2, acc1);
    acc2 = fmaf(h2.z, w2, acc2); acc3 = fmaf(h3.z, w2, acc3);
    acc0 = fmaf(h0.w, w3, acc0); acc1 = fmaf(h1.w, w3, acc1);
    acc2 = fmaf(h2.w, w3, acc2); acc3 = fmaf(h3.w, w3, acc3);
  }
  float* Ob = O + (size_t)(a0 + ah*4) * 640 + fam * 128 + f1;
  Ob[0]    = acc0;
  Ob[640]  = acc1;
  Ob[1280] = acc2;
  Ob[1920] = acc3;
}

// Node 2: fused filter + per-edge MLP. No weight LDS staging: L1 RBF weights
// direct from L2 (32 unrolled coalesced loads, shared across 2 edges); W2
// k-split across waves (wave = k-quarter, lane = out-feat, shared across all
// 4 edges); quarter-partials combined in LDS. One atomic per edge.
__global__ __launch_bounds__(256) void fused_kernel(
    const int* __restrict__ pe, const float* __restrict__ pdisp,
    const float* __restrict__ cell, const float* __restrict__ atom_xyz,
    const float* __restrict__ probe_xyz,
    const float* __restrict__ O,
    const float* __restrict__ W1, const float* __restrict__ b1,
    const float* __restrict__ W2, const float* __restrict__ b2,
    const float* __restrict__ W3, const float* __restrict__ b3,
    float* __restrict__ out) {
  __shared__ float sdx[CHUNK], sdy[CHUNK], sdz[CHUNK];   // 3 KB
  __shared__ unsigned sap[CHUNK];                        // 1 KB
  __shared__ int mcnt;
  __shared__ float epS[NE][DRBF];       // 0.5 KB
  __shared__ float h2S[NE][FH];         // 2 KB
  __shared__ float part2[4][NE][64];    // 4 KB
  __shared__ float rS[NE][3];
  __shared__ unsigned aS[NE];
  __shared__ float cwS[NE];
  __shared__ unsigned pS[NE];

  const int t    = threadIdx.x;
  const int lane = t & 63;
  const int wave = t >> 6;
  if (t == 0) mcnt = 0;
  __syncthreads();

  // ---- Phase F: filter this block's 256 edges (1/thread) ----
  const int e = blockIdx.x * CHUNK + t;
  const int b = blockIdx.x >> 7;          // 128 blocks per batch
  const float* cb = cell + b * 9;
  {
    int2 ap = ((const int2*)pe)[e];
    float pd0 = pdisp[e*3], pd1 = pdisp[e*3+1], pd2 = pdisp[e*3+2];
    float d0 = pd0*cb[0] + pd1*cb[3] + pd2*cb[6];
    float d1 = pd0*cb[1] + pd1*cb[4] + pd2*cb[7];
    float d2 = pd0*cb[2] + pd1*cb[5] + pd2*cb[8];
    int ag = b*NN + ap.x;
    int pg = b*PP + ap.y;
    float dx = probe_xyz[pg*3]   - (atom_xyz[ag*3]   + d0);
    float dy = probe_xyz[pg*3+1] - (atom_xyz[ag*3+1] + d1);
    float dz = probe_xyz[pg*3+2] - (atom_xyz[ag*3+2] + d2);
    float dist2 = dx*dx + dy*dy + dz*dz;
    if (dist2 < CUT*CUT) {
      int s = atomicAdd(&mcnt, 1);   // LDS atomic
      sdx[s] = dx; sdy[s] = dy; sdz[s] = dz;
      sap[s] = ((unsigned)ag << 16) | (unsigned)pg;
    }
  }
  __syncthreads();
  const int m = mcnt;
  if (m == 0) return;

  const int f1 = t & 127;     // L1 feature
  const int eh = t >> 7;      // L1 edge-half (edges eh*2, eh*2+1)
  const float b1v = b1[f1];
  const float b2v = b2[lane];
  const float w3v = W3[lane];
  const float b3v = b3[0];

  for (int s0 = 0; s0 < m; s0 += NE) {
    // ---- per-edge prep: wave w handles survivor s0+w ----
    {
      const int s = s0 + wave;
      float dx, dy, dz; unsigned ap_;
      if (s < m) { dx = sdx[s]; dy = sdy[s]; dz = sdz[s]; ap_ = sap[s]; }
      else       { dx = 1.f; dy = 0.f; dz = 0.f; ap_ = 0xFFFFFFFFu; }
      float d = sqrtf(dx*dx + dy*dy + dz*dz);
      float inv = 1.0f / (d + 1e-8f);
      if (lane < DRBF) epS[wave][lane] = sinf(d * (float)(lane+1) * (PI_F/CUT)) / d;
      if (lane == 0) {
        rS[wave][0] = dx*inv; rS[wave][1] = dy*inv; rS[wave][2] = dz*inv;
        aS[wave] = (ap_ == 0xFFFFFFFFu) ? 0u : (ap_ >> 16);
        cwS[wave] = 0.5f * (cosf((PI_F/CUT) * d) + 1.0f);
        pS[wave]  = (ap_ == 0xFFFFFFFFu) ? 0xFFFFFFFFu : (ap_ & 0xFFFFu);
      }
    }
    __syncthreads();

    // ---- L1: thread (f1, eh) -> z for edges eh*2, eh*2+1 ----
    {
      const int e0 = eh*2, e1 = eh*2 + 1;
      const float* Ob0 = O + (size_t)aS[e0] * 640 + f1;
      const float* Ob1 = O + (size_t)aS[e1] * 640 + f1;
      float o00 = Ob0[0], o01 = Ob0[128], o02 = Ob0[256], o03 = Ob0[384], o04 = Ob0[512];
      float o10 = Ob1[0], o11 = Ob1[128], o12 = Ob1[256], o13 = Ob1[384], o14 = Ob1[512];
      float z0 = b1v + o03 + o04 + rS[e0][0]*o00 + rS[e0][1]*o01 + rS[e0][2]*o02;
      float z1 = b1v + o13 + o14 + rS[e1][0]*o10 + rS[e1][1]*o11 + rS[e1][2]*o12;
      const float* Wb = W1 + f1;          // RBF rows 0..31, coalesced per-lane
      #pragma unroll
      for (int k = 0; k < DRBF; ++k) {
        float w = Wb[k * FH];
        z0 = fmaf(epS[e0][k], w, z0);
        z1 = fmaf(epS[e1][k], w, z1);
      }
      h2S[e0][f1] = z0 / (1.0f + __expf(-z0));
      h2S[e1][f1] = z1 / (1.0f + __expf(-z1));
    }
    __syncthreads();

    // ---- L2 (k-split): wave = k-quarter, lane = out-feature ----
    {
      float a0 = 0.f, a1 = 0.f, a2 = 0.f, a3 = 0.f;
      const float* Wq = W2 + (wave * 32) * 64 + lane;   // coalesced per-lane
      const float* h0p = &h2S[0][wave * 32];
      const float* h1p = &h2S[1][wave * 32];
      const float* h2p = &h2S[2][wave * 32];
      const float* h3p = &h2S[3][wave * 32];
      #pragma unroll
      for (int k4 = 0; k4 < 8; ++k4) {
        float w0 = Wq[(k4*4 + 0) * 64];
        float w1 = Wq[(k4*4 + 1) * 64];
        float w2 = Wq[(k4*4 + 2) * 64];
        float w3 = Wq[(k4*4 + 3) * 64];
        float4 h0 = *(const float4*)&h0p[k4*4];
        float4 h1 = *(const float4*)&h1p[k4*4];
        float4 h2 = *(const float4*)&h2p[k4*4];
        float4 h3 = *(const float4*)&h3p[k4*4];
        a0 = fmaf(h0.x, w0, a0); a1 = fmaf(h1.x, w0, a1);
        a2 = fmaf(h2.x, w0, a2); a3 = fmaf(h3.x, w0, a3);
        a0 = fmaf(h0.y, w1, a0); a1 = fmaf(h1.y, w1, a1);
        a2 = fmaf(h2.y, w1, a2); a3 = fmaf(h3.y, w1, a3);
        a0 = fmaf(h0.z, w2, a0); a1 = fmaf(h1.z, w2, a1);
        a2 = fmaf(h2.z, w2, a2); a3 = fmaf(h3.z, w2, a3);
        a0 = fmaf(h0.w, w3, a0); a1 = fmaf(h1.w, w3, a1);
        a2 = fmaf(h2.w, w3, a2); a3 = fmaf(h3.w, w3, a3);
      }
      part2[wave][0][lane] = a0;
      part2[wave][1][lane] = a1;
      part2[wave][2][lane] = a2;
      part2[wave][3][lane] = a3;
    }
    __syncthreads();

    // ---- finish: wave = edge, lane = out-feature; silu + W3-dot + scatter ----
    {
      float z = part2[0][wave][lane] + part2[1][wave][lane]
              + part2[2][wave][lane] + part2[3][wave][lane] + b2v;
      float h2 = z / (1.0f + __expf(-z));
      float rs = h2 * w3v;
      #pragma unroll
      for (int off = 32; off; off >>= 1) rs += __shfl_xor(rs, off, 64);
      if (lane == 0) {
        unsigned p = pS[wave];
        if (p != 0xFFFFFFFFu) atomicAdd(&out[p], (rs + b3v) * cwS[wave]);
      }
    }
    __syncthreads();
  }
}

extern "C" void kernel_launch(void* const* d_in, const int* in_sizes, int n_in,
                              void* d_out, int out_size, void* d_ws, size_t ws_size,
                              hipStream_t stream) {
  const float* S         = (const float*)d_in[0];
  const float* V         = (const float*)d_in[1];
  const float* atom_xyz  = (const float*)d_in[2];
  const float* probe_xyz = (const float*)d_in[3];
  const float* cell      = (const float*)d_in[4];
  const float* pdisp     = (const float*)d_in[5];
  const float* W1        = (const float*)d_in[6];
  const float* b1        = (const float*)d_in[7];
  const float* W2        = (const float*)d_in[8];
  const float* b2        = (const float*)d_in[9];
  const float* W3        = (const float*)d_in[10];
  const float* b3        = (const float*)d_in[11];
  const int*   pe        = (const int*)d_in[12];
  float* out = (float*)d_out;

  float* O = (float*)((char*)d_ws + 256);   // 2048 x 640 floats

  atom_kernel<<<(BB*NN/AT2)*5, 256, 0, stream>>>(S, V, W1, O, out);
  fused_kernel<<<BB*EE/CHUNK, 256, 0, stream>>>(pe, pdisp, cell, atom_xyz, probe_xyz,
                                                O, W1, b1, W2, b2, W3, b3, out);
}